// Round 7
// baseline (92.853 us; speedup 1.0000x reference)
//
#include <hip/hip_runtime.h>
#include <hip/hip_bf16.h>

// out[i] = x_i @ Q @ x_i, x [1024,2048] fp32 binary, Q [2048,2048] fp32.
// Identity: x^T Q x == x^T Q^T x -> MFMA B-operand (N x K) = row-major Q.
// Round 7: SINGLE fused GEMM (no prep kernel, no bf16 round-trip): fp32
// global loads -> v_cvt -> XOR-swizzled ds_write_b128. Register staging makes
// barriers drain only LDS ops (not vmcnt(0) like global_load_lds), and lets
// iter1 / mask loads fly during iter0 / iter1 MFMAs. Keeps R6's wins:
// KSPLIT=16, contention-free partials + tiny reduce, LDS-mask epilogue.

#define B_ROWS 1024
#define N_BITS 2048

#define BM 128
#define BN 128
#define BK 64
#define KSPLIT 16
#define KPER (N_BITS / KSPLIT)   // 128
#define NKB (N_BITS / BN)        // 16
#define NPART (NKB * KSPLIT)     // 256 partials per row

typedef __bf16 bf16_t;
typedef __bf16 bf16x8 __attribute__((ext_vector_type(8)));
typedef float f32x4 __attribute__((ext_vector_type(4)));

// GEMM S = X @ Q^T (16x16x32 frags, R2/R6 engine) + LDS-masked row-dot.
// 4 waves split M (each 32 rows x 128 cols, acc 2x8). Partials, no atomics.
__global__ __launch_bounds__(256, 3) void qubo_fused(
    const float* __restrict__ X, const float* __restrict__ Qm,
    float* __restrict__ partial) {
  __shared__ bf16_t lds[(BM + BN) * BK];   // 32 KB; A at 0, B at BM*BK
  bf16_t* ldsA = lds;
  bf16_t* ldsB = lds + BM * BK;

  const int tid  = threadIdx.x;
  const int lane = tid & 63;
  const int wave = tid >> 6;
  const int lrow = lane & 15;
  const int quad = lane >> 4;

  const int m0    = blockIdx.y * BM;
  const int n0    = blockIdx.x * BN;
  const int kbase = blockIdx.z * KPER;
  const int nkid  = blockIdx.x * KSPLIT + blockIdx.z;  // 0..255

  // Staging: chunk = 8 bf16 (2 float4 in global). Per tile 128 rows x 8
  // chunks = 4/thread. Global chunk g = tid&7 of row r lands in LDS slot
  // g ^ (r&7)  -> frag ds_read_b128 un-swizzles with ^ (lrow&7). Write
  // pattern covers all 32 banks (conflict-free); R6-verified math.
  const int srow = tid >> 3;                      // 0..31
  const int swz  = ((tid & 7) ^ (srow & 7)) * 8;  // lds col (elems)

  f32x4 acc[2][8];
#pragma unroll
  for (int i = 0; i < 2; ++i)
#pragma unroll
    for (int j = 0; j < 8; ++j) acc[i][j] = (f32x4){0.f, 0.f, 0.f, 0.f};

  float4 rA[4][2], rB[4][2];   // one K-iter's staging (64 VGPRs)

#define LOAD_AB(kt)                                                           \
  {                                                                           \
    const int k0 = kbase + (kt) * BK;                                         \
    _Pragma("unroll")                                                         \
    for (int p = 0; p < 4; ++p) {                                             \
      const float4* ga =                                                      \
          (const float4*)(X + (size_t)(m0 + p * 32 + srow) * N_BITS + k0 +    \
                          (tid & 7) * 8);                                     \
      rA[p][0] = ga[0]; rA[p][1] = ga[1];                                     \
      const float4* gb =                                                      \
          (const float4*)(Qm + (size_t)(n0 + p * 32 + srow) * N_BITS + k0 +   \
                          (tid & 7) * 8);                                     \
      rB[p][0] = gb[0]; rB[p][1] = gb[1];                                     \
    }                                                                         \
  }

#define CVT_STORE(dstBase, r0, r1)                                            \
  {                                                                           \
    union { int4 i4; __hip_bfloat162 h2[4]; } u;                              \
    u.h2[0] = __float22bfloat162_rn(make_float2((r0).x, (r0).y));             \
    u.h2[1] = __float22bfloat162_rn(make_float2((r0).z, (r0).w));             \
    u.h2[2] = __float22bfloat162_rn(make_float2((r1).x, (r1).y));             \
    u.h2[3] = __float22bfloat162_rn(make_float2((r1).z, (r1).w));             \
    *(int4*)(dstBase) = u.i4;                                                 \
  }

#define STORE_AB()                                                            \
  {                                                                           \
    _Pragma("unroll")                                                         \
    for (int p = 0; p < 4; ++p) {                                             \
      const int r = p * 32 + srow;                                            \
      CVT_STORE(ldsA + r * BK + swz, rA[p][0], rA[p][1]);                     \
      CVT_STORE(ldsB + r * BK + swz, rB[p][0], rB[p][1]);                     \
    }                                                                         \
  }

#define MFMA_ITER()                                                           \
  {                                                                           \
    _Pragma("unroll")                                                         \
    for (int ks = 0; ks < 2; ++ks) {                                          \
      const int ch = ((ks * 4 + quad) ^ (lrow & 7)) * 8;                      \
      bf16x8 a[2], b[8];                                                      \
      _Pragma("unroll")                                                       \
      for (int mi = 0; mi < 2; ++mi)                                          \
        a[mi] = *(const bf16x8*)&ldsA[(wave * 32 + mi * 16 + lrow) * BK + ch];\
      _Pragma("unroll")                                                       \
      for (int ni = 0; ni < 8; ++ni)                                          \
        b[ni] = *(const bf16x8*)&ldsB[(ni * 16 + lrow) * BK + ch];            \
      _Pragma("unroll")                                                       \
      for (int mi = 0; mi < 2; ++mi)                                          \
        _Pragma("unroll")                                                     \
        for (int ni = 0; ni < 8; ++ni)                                        \
          acc[mi][ni] = __builtin_amdgcn_mfma_f32_16x16x32_bf16(              \
              a[mi], b[ni], acc[mi][ni], 0, 0, 0);                            \
    }                                                                         \
  }

  // --- pipelined 2-iteration K-loop (KPER=128, BK=64) ---
  LOAD_AB(0);
  STORE_AB();
  __syncthreads();           // LDS-only drain (loads went to registers)
  LOAD_AB(1);                // in flight during MFMA iter0
  MFMA_ITER();
  __syncthreads();           // iter0 LDS reads done before overwrite
  STORE_AB();
  __syncthreads();

  // mask tile X[m0:+128, n0:+128] -> bf16 LDS (overlays A/B buffers).
  const int mrow = tid >> 4;           // 0..15
  const int mc   = (tid & 15) * 8;     // col (elems)
  float4 rM[8][2];
#pragma unroll
  for (int p = 0; p < 8; ++p) {        // issued during MFMA iter1
    const float4* gm =
        (const float4*)(X + (size_t)(m0 + p * 16 + mrow) * N_BITS + n0 + mc);
    rM[p][0] = gm[0]; rM[p][1] = gm[1];
  }
  MFMA_ITER();
  __syncthreads();           // iter1 LDS reads done before mask overwrite
  bf16_t* maskL = lds;
#pragma unroll
  for (int p = 0; p < 8; ++p)
    CVT_STORE(maskL + (p * 16 + mrow) * BN + mc, rM[p][0], rM[p][1]);
  __syncthreads();

  // Epilogue. 16x16 C/D: col = lane&15, row = quad*4 + reg. Mask from LDS,
  // 16-lane shuffle reduce, one plain store per (row, nkid). No atomics.
#pragma unroll
  for (int mi = 0; mi < 2; ++mi) {
#pragma unroll
    for (int r = 0; r < 4; ++r) {
      const int rloc = wave * 32 + mi * 16 + quad * 4 + r;
      float s = 0.f;
#pragma unroll
      for (int ni = 0; ni < 8; ++ni)
        s += acc[mi][ni][r] * (float)maskL[rloc * BN + ni * 16 + lrow];
#pragma unroll
      for (int off = 1; off < 16; off <<= 1)
        s += __shfl_xor(s, off, 64);
      if (lrow == 0)
        partial[(size_t)(m0 + rloc) * NPART + nkid] = s;
    }
  }
}

// reduce: out[row] = sum of 256 partials. One block per row, coalesced.
__global__ __launch_bounds__(256) void reduce_kernel(
    const float* __restrict__ partial, float* __restrict__ out) {
  const int row = blockIdx.x;
  const int tid = threadIdx.x;
  float v = partial[(size_t)row * NPART + tid];
#pragma unroll
  for (int off = 1; off < 64; off <<= 1)
    v += __shfl_xor(v, off, 64);
  __shared__ float wsum[4];
  if ((tid & 63) == 0) wsum[tid >> 6] = v;
  __syncthreads();
  if (tid == 0) out[row] = wsum[0] + wsum[1] + wsum[2] + wsum[3];
}

extern "C" void kernel_launch(void* const* d_in, const int* in_sizes, int n_in,
                              void* d_out, int out_size, void* d_ws, size_t ws_size,
                              hipStream_t stream) {
  const float* x = (const float*)d_in[0];
  const float* Q = (const float*)d_in[1];
  float* out = (float*)d_out;
  float* partial = (float*)d_ws;   // 1 MB

  dim3 grid(NKB, B_ROWS / BM, KSPLIT);  // (16, 8, 16) = 2048 blocks
  qubo_fused<<<grid, dim3(256), 0, stream>>>(x, Q, partial);

  reduce_kernel<<<B_ROWS, 256, 0, stream>>>(partial, out);
}